// Round 10
// baseline (2436.458 us; speedup 1.0000x reference)
//
#include <hip/hip_runtime.h>
#include <cstddef>
#include <cstdint>

// K-means (Lloyd, 10 fixed iters): N=1024 pts, K=64 centroids, D=98304.
// d_in[0]=x f32[1024*98304], d_in[1]=centroid f32[64*98304]
// d_out = concat(final state [64*98304] f32, last choice [1024] as f32)
//
// Round 10: (a) gbuild: NGRP back to 16 (72-block XCD queue) + LDS padded to
// 56KB -> 2 blocks/CU so only ~1 epoch is resident per XCD (round 8's 1.38x
// FETCH) while keeping round 9's async global_load_lds + XOR swizzle (0 bank
// conflicts); (b) iteration loop fused into step_kernel (c2+assign+sort+out),
// 41 -> 19 launches, identical serial-ascending reduction orders.

#define N_PTS  1024
#define K_C    64
#define D_DIM  98304
#define ITERS  10
#define SPLITD 64          // init dot kernel split
#define BM     64
#define DC     64
#define LDSP   72
#define NCHK   96          // D/1024
#define CCHK   12          // D/8192
#define NGRP   16          // seg-half groups (2 XCD-cohort epochs x 8)
#define SHPG   12          // seg-halves per group
#define SHW    512         // shorts per seg-half
#define NCHT   192         // chunks per block = SHPG * SHW/GDC
#define NPAIR  36          // 8x8 upper-triangle 128-tiles
#define GT     128
#define GDC    32          // dims per K-chunk

typedef __attribute__((ext_vector_type(8))) short bf16x8;
typedef __attribute__((ext_vector_type(8))) unsigned short ushort8;
typedef __attribute__((ext_vector_type(4))) float f32x4;

__device__ __forceinline__ unsigned short f2bf(float x) {   // RNE f32->bf16
    unsigned u = __float_as_uint(x);
    u = (u + 0x7FFFu + ((u >> 16) & 1u)) >> 16;
    return (unsigned short)u;
}
__device__ __forceinline__ float bf2f(unsigned short b) {
    return __uint_as_float((unsigned)b << 16);
}
__device__ __forceinline__ void cvt2(float x, unsigned short& h, unsigned short& l) {
    h = f2bf(x);
    l = f2bf(x - bf2f(h));
}

__device__ __forceinline__ void gload_lds16(const unsigned short* g, char* l) {
    __builtin_amdgcn_global_load_lds(
        (const __attribute__((address_space(1))) unsigned int*)g,
        (__attribute__((address_space(3))) unsigned int*)l, 16, 0, 0);
}

__device__ __forceinline__ float block_sum256(float s) {
    #pragma unroll
    for (int o = 32; o; o >>= 1) s += __shfl_down(s, o);
    __shared__ float red[4];
    int lane = threadIdx.x & 63, w = threadIdx.x >> 6;
    if (lane == 0) red[w] = s;
    __syncthreads();
    return red[0] + red[1] + red[2] + red[3];
}

// ---------------- convert rows fp32 -> bf16 hi/lo planes + sumsq partials ----------------
__global__ __launch_bounds__(256) void convert_kernel(const float* __restrict__ A,
                                                      unsigned short* __restrict__ Ph,
                                                      unsigned short* __restrict__ Pl,
                                                      float* __restrict__ sq_part) {
    const int n = blockIdx.x, j = blockIdx.y;
    const size_t base = (size_t)n * D_DIM + (size_t)j * 8192;
    const int t = threadIdx.x;
    float ss = 0.f;
    #pragma unroll
    for (int i = 0; i < 4; ++i) {
        size_t e = base + (size_t)i * 2048 + t * 8;
        float4 a = *reinterpret_cast<const float4*>(A + e);
        float4 b = *reinterpret_cast<const float4*>(A + e + 4);
        ss += a.x*a.x + a.y*a.y + a.z*a.z + a.w*a.w;
        ss += b.x*b.x + b.y*b.y + b.z*b.z + b.w*b.w;
        ushort4 h0, l0, h1, l1;
        cvt2(a.x, h0.x, l0.x); cvt2(a.y, h0.y, l0.y);
        cvt2(a.z, h0.z, l0.z); cvt2(a.w, h0.w, l0.w);
        cvt2(b.x, h1.x, l1.x); cvt2(b.y, h1.y, l1.y);
        cvt2(b.z, h1.z, l1.z); cvt2(b.w, h1.w, l1.w);
        *reinterpret_cast<ushort4*>(Ph + e)     = h0;
        *reinterpret_cast<ushort4*>(Ph + e + 4) = h1;
        *reinterpret_cast<ushort4*>(Pl + e)     = l0;
        *reinterpret_cast<ushort4*>(Pl + e + 4) = l1;
    }
    ss = block_sum256(ss);
    if (t == 0) sq_part[n * CCHK + j] = ss;
}

__global__ __launch_bounds__(256) void reduce_sq_kernel(const float* __restrict__ sq_part,
                                                        float* __restrict__ out, int rows) {
    int n = blockIdx.x * 256 + threadIdx.x;
    if (n >= rows) return;
    float s = 0.f;
    #pragma unroll
    for (int j = 0; j < CCHK; ++j) s += sq_part[n * CCHK + j];
    out[n] = s;
}

// ---------------- init dot vs C0: bf16 hi/lo x3 MFMA, A direct-global ----------------
__global__ __launch_bounds__(256) void mfma_dot_kernel(const unsigned short* __restrict__ Xh,
                                                       const unsigned short* __restrict__ Xl,
                                                       const unsigned short* __restrict__ Sh,
                                                       const unsigned short* __restrict__ Sl,
                                                       float* __restrict__ partial) {
    __shared__ alignas(16) short Bh[K_C][LDSP];
    __shared__ alignas(16) short Bl[K_C][LDSP];

    const int seg = blockIdx.x, nblk = blockIdx.y;
    const int t = threadIdx.x;
    const int wid = t >> 6, lane = t & 63;
    const int d_begin = seg * (D_DIM / SPLITD);
    const int NCH = (D_DIM / SPLITD) / DC;          // 24 (even)

    const int arow = nblk * BM + wid * 16 + (lane & 15);
    const int ko = (lane >> 4) * 8;
    const unsigned short* xh = Xh + (size_t)arow * D_DIM;
    const unsigned short* xl = Xl + (size_t)arow * D_DIM;

    const int sr = t >> 2, sc = (t & 3) * 16;
    const unsigned short* shp = Sh + (size_t)sr * D_DIM;
    const unsigned short* slp = Sl + (size_t)sr * D_DIM;

    ushort8 s0, s1, s2, s3;
    bf16x8 aEh0, aEh1, aEl0, aEl1;
    bf16x8 aOh0, aOh1, aOl0, aOl1;

    auto loadB = [&](int d0) {
        s0 = *reinterpret_cast<const ushort8*>(shp + d0 + sc);
        s1 = *reinterpret_cast<const ushort8*>(shp + d0 + sc + 8);
        s2 = *reinterpret_cast<const ushort8*>(slp + d0 + sc);
        s3 = *reinterpret_cast<const ushort8*>(slp + d0 + sc + 8);
    };
    auto storeB = [&]() {
        *reinterpret_cast<ushort8*>(&Bh[sr][sc])     = s0;
        *reinterpret_cast<ushort8*>(&Bh[sr][sc + 8]) = s1;
        *reinterpret_cast<ushort8*>(&Bl[sr][sc])     = s2;
        *reinterpret_cast<ushort8*>(&Bl[sr][sc + 8]) = s3;
    };

    f32x4 acc[4];
    #pragma unroll
    for (int i = 0; i < 4; ++i) acc[i] = f32x4{0.f, 0.f, 0.f, 0.f};

    #define LOADA(bh0, bh1, bl0, bl1, d0)                                        \
        bh0 = *reinterpret_cast<const bf16x8*>(xh + (d0) + ko);                  \
        bh1 = *reinterpret_cast<const bf16x8*>(xh + (d0) + 32 + ko);             \
        bl0 = *reinterpret_cast<const bf16x8*>(xl + (d0) + ko);                  \
        bl1 = *reinterpret_cast<const bf16x8*>(xl + (d0) + 32 + ko);

    #define MFMAS(ah0, ah1, al0, al1)                                            \
        _Pragma("unroll")                                                        \
        for (int nb = 0; nb < 4; ++nb) {                                         \
            const int br = nb * 16 + (lane & 15);                                \
            bf16x8 bh = *reinterpret_cast<const bf16x8*>(&Bh[br][ko]);           \
            bf16x8 bl = *reinterpret_cast<const bf16x8*>(&Bl[br][ko]);           \
            acc[nb] = __builtin_amdgcn_mfma_f32_16x16x32_bf16(ah0, bh, acc[nb], 0, 0, 0); \
            acc[nb] = __builtin_amdgcn_mfma_f32_16x16x32_bf16(ah0, bl, acc[nb], 0, 0, 0); \
            acc[nb] = __builtin_amdgcn_mfma_f32_16x16x32_bf16(al0, bh, acc[nb], 0, 0, 0); \
        }                                                                        \
        _Pragma("unroll")                                                        \
        for (int nb = 0; nb < 4; ++nb) {                                         \
            const int br = nb * 16 + (lane & 15);                                \
            bf16x8 bh = *reinterpret_cast<const bf16x8*>(&Bh[br][32 + ko]);      \
            bf16x8 bl = *reinterpret_cast<const bf16x8*>(&Bl[br][32 + ko]);      \
            acc[nb] = __builtin_amdgcn_mfma_f32_16x16x32_bf16(ah1, bh, acc[nb], 0, 0, 0); \
            acc[nb] = __builtin_amdgcn_mfma_f32_16x16x32_bf16(ah1, bl, acc[nb], 0, 0, 0); \
            acc[nb] = __builtin_amdgcn_mfma_f32_16x16x32_bf16(al1, bh, acc[nb], 0, 0, 0); \
        }

    loadB(d_begin);
    LOADA(aEh0, aEh1, aEl0, aEl1, d_begin);
    for (int c = 0; c < NCH; c += 2) {
        __syncthreads();
        storeB();
        __syncthreads();
        {
            int dn = d_begin + (c + 1) * DC;
            loadB(dn);
            LOADA(aOh0, aOh1, aOl0, aOl1, dn);
        }
        MFMAS(aEh0, aEh1, aEl0, aEl1);
        __syncthreads();
        storeB();
        __syncthreads();
        if (c + 2 < NCH) {
            int dn = d_begin + (c + 2) * DC;
            loadB(dn);
            LOADA(aEh0, aEh1, aEl0, aEl1, dn);
        }
        MFMAS(aOh0, aOh1, aOl0, aOl1);
    }
    #undef LOADA
    #undef MFMAS

    #pragma unroll
    for (int nb = 0; nb < 4; ++nb)
        #pragma unroll
        for (int r = 0; r < 4; ++r) {
            int row = wid * 16 + (lane >> 4) * 4 + r;
            int col = nb * 16 + (lane & 15);
            int n = nblk * BM + row;
            partial[((size_t)seg * N_PTS + n) * K_C + col] = acc[nb][r];
        }
}

__global__ __launch_bounds__(256) void reduce_dot_kernel(const float* __restrict__ partial,
                                                         float* __restrict__ dot) {
    int i = blockIdx.x * 256 + threadIdx.x;
    float s = 0.f;
    #pragma unroll 8
    for (int p = 0; p < SPLITD; ++p) s += partial[(size_t)p * N_PTS * K_C + i];
    dot[i] = s;
}

__global__ __launch_bounds__(256) void argmin_n_kernel(const float* __restrict__ dot,
                                                       const float* __restrict__ x2,
                                                       int* __restrict__ choice_pts) {
    int k = blockIdx.x;
    float best = 3.4e38f; int bi = N_PTS;
    for (int n = threadIdx.x; n < N_PTS; n += 256) {
        float v = fmaf(-2.f, dot[n * K_C + k], x2[n]);
        if (v < best || (v == best && n < bi)) { best = v; bi = n; }
    }
    #pragma unroll
    for (int off = 32; off; off >>= 1) {
        float v2 = __shfl_down(best, off);
        int   i2 = __shfl_down(bi, off);
        if (v2 < best || (v2 == best && i2 < bi)) { best = v2; bi = i2; }
    }
    __shared__ float bv[4]; __shared__ int bix[4];
    int lane = threadIdx.x & 63, wid = threadIdx.x >> 6;
    if (lane == 0) { bv[wid] = best; bix[wid] = bi; }
    __syncthreads();
    if (threadIdx.x == 0) {
        for (int w = 1; w < 4; ++w)
            if (bv[w] < best || (bv[w] == best && bix[w] < bi)) { best = bv[w]; bi = bix[w]; }
        choice_pts[k] = bi;
    }
}

// ---------------- gather snapped centroids (exact fp32) ----------------
__global__ __launch_bounds__(256) void gather_kernel(const float* __restrict__ X,
                                                     const int* __restrict__ choice_pts,
                                                     float* __restrict__ state) {
    int k = blockIdx.x;
    int c = choice_pts[k];
    size_t d = (size_t)blockIdx.y * 1024 + threadIdx.x * 4;
    float4 v = *reinterpret_cast<const float4*>(X + (size_t)c * D_DIM + d);
    *reinterpret_cast<float4*>(state + (size_t)k * D_DIM + d) = v;
}

// ---------------- G = X.X^T: async-staged, swizzled-LDS, XCD-cohort ----------------
// 576 blocks; id=(g%8)+8*(p+36*(g/8)) keeps all 36 pairs of a group on one
// XCD. LDS padded to 56KB -> 2 blocks/CU (64 slots/XCD < 72-block epoch =>
// ~1 epoch resident => L2 slice stays hot). Staging/swizzle identical to r9:
// logical word w of row r at (w^(r&7))*16; source pre-swizzled per lane.
__global__ __launch_bounds__(256, 2) void gbuild_kernel(const unsigned short* __restrict__ Xh,
                                                        const unsigned short* __restrict__ Xl,
                                                        float* __restrict__ Gpart) {
    __shared__ alignas(16) char LA[16384 + 12288];   // +pad: 56KB/block => 2 blocks/CU
    __shared__ alignas(16) char LB[16384 + 12288];

    const int id = blockIdx.x;
    const int xr = id & 7, q = id >> 3;
    const int p = q % NPAIR;
    const int g = ((q / NPAIR) << 3) + xr;          // 0..15
    int bi = 0, rem = p, rl = 8;
    while (rem >= rl) { rem -= rl; --rl; ++bi; }
    const int bj = bi + rem;

    const int t = threadIdx.x;
    const int wid = t >> 6, lane = t & 63;
    const int wr = wid >> 1, wc = wid & 1;

    // --- staging setup: waves 0-1 stage A (rows bi*128..), waves 2-3 stage B ---
    const int isA = (wid < 2) ? 1 : 0;
    const int i0 = (wid & 1) * 8;                   // instr indices i0..i0+7
    char* ltile = isA ? LA : LB;
    const int rowbase = (isA ? bi : bj) * GT;
    const int lw = (lane & 7) ^ (lane >> 3);        // logical word this lane fetches
    const unsigned short* plane = (lw & 4) ? Xl : Xh;
    const unsigned short* gbase[8];
    #pragma unroll
    for (int j = 0; j < 8; ++j)
        gbase[j] = plane + (size_t)(rowbase + (i0 + j) * 8 + (lane >> 3)) * D_DIM + (lw & 3) * 8;

    // --- read setup: r&7 == lane&7 for all fragments ---
    const int sh = (lane >> 4) ^ (lane & 7);        // slot, plane hi (w = lane>>4)
    const int sl = (4 + (lane >> 4)) ^ (lane & 7);  // slot, plane lo (w = 4+lane>>4)
    const int ra0 = (wr * 64 + (lane & 15)) * 128;
    const int rb0 = (wc * 64 + (lane & 15)) * 128;

    f32x4 acc[4][4];
    #pragma unroll
    for (int i = 0; i < 4; ++i)
        #pragma unroll
        for (int j = 0; j < 4; ++j) acc[i][j] = f32x4{0.f, 0.f, 0.f, 0.f};

    for (int idx = 0; idx < NCHT; ++idx) {
        const int d0 = (g + ((idx >> 4) << 4)) * SHW + (idx & 15) * GDC;
        __syncthreads();                            // prior chunk's frag reads done
        #pragma unroll
        for (int j = 0; j < 8; ++j)
            gload_lds16(gbase[j] + d0, ltile + (i0 + j) * 1024);
        __syncthreads();                            // vmcnt(0) drained before barrier
        bf16x8 ah[4], al[4];
        #pragma unroll
        for (int fi = 0; fi < 4; ++fi) {
            ah[fi] = *reinterpret_cast<const bf16x8*>(LA + ra0 + fi * 2048 + sh * 16);
            al[fi] = *reinterpret_cast<const bf16x8*>(LA + ra0 + fi * 2048 + sl * 16);
        }
        #pragma unroll
        for (int fj = 0; fj < 4; ++fj) {
            bf16x8 bh = *reinterpret_cast<const bf16x8*>(LB + rb0 + fj * 2048 + sh * 16);
            bf16x8 bl = *reinterpret_cast<const bf16x8*>(LB + rb0 + fj * 2048 + sl * 16);
            #pragma unroll
            for (int fi = 0; fi < 4; ++fi) {
                acc[fi][fj] = __builtin_amdgcn_mfma_f32_16x16x32_bf16(ah[fi], bh, acc[fi][fj], 0, 0, 0);
                acc[fi][fj] = __builtin_amdgcn_mfma_f32_16x16x32_bf16(ah[fi], bl, acc[fi][fj], 0, 0, 0);
                acc[fi][fj] = __builtin_amdgcn_mfma_f32_16x16x32_bf16(al[fi], bh, acc[fi][fj], 0, 0, 0);
            }
        }
    }

    float* gp = Gpart + ((size_t)g * NPAIR + p) * (GT * GT);
    #pragma unroll
    for (int fi = 0; fi < 4; ++fi)
        #pragma unroll
        for (int fj = 0; fj < 4; ++fj)
            #pragma unroll
            for (int r2 = 0; r2 < 4; ++r2) {
                int row = wr * 64 + fi * 16 + (lane >> 4) * 4 + r2;
                int col = wc * 64 + fj * 16 + (lane & 15);
                gp[row * GT + col] = acc[fi][fj][r2];
            }
}

// ---------------- reduce G partials over groups + mirror to lower triangle ----------------
__global__ __launch_bounds__(256) void reduce_g_kernel(const float* __restrict__ Gpart,
                                                       float* __restrict__ G) {
    const int p = blockIdx.x, blk = blockIdx.y;     // grid (NPAIR, 16)
    int bi = 0, rem = p, rl = 8;
    while (rem >= rl) { rem -= rl; --rl; ++bi; }
    const int bj = bi + rem;
    const int e0 = blk * 1024 + threadIdx.x * 4;
    float sx = 0.f, sy = 0.f, sz = 0.f, sw = 0.f;
    #pragma unroll 8
    for (int g = 0; g < NGRP; ++g) {
        const float4 v = *reinterpret_cast<const float4*>(
            Gpart + ((size_t)g * NPAIR + p) * (GT * GT) + e0);
        sx += v.x; sy += v.y; sz += v.z; sw += v.w;
    }
    const int row = e0 >> 7, col = e0 & 127;
    const int gi = bi * GT + row, gj = bj * GT + col;
    float4 o = {sx, sy, sz, sw};
    *reinterpret_cast<float4*>(&G[(size_t)gi * N_PTS + gj]) = o;
    if (bi != bj) {                                 // mirror (single writer per elem)
        G[(size_t)(gj + 0) * N_PTS + gi] = sx;
        G[(size_t)(gj + 1) * N_PTS + gi] = sy;
        G[(size_t)(gj + 2) * N_PTS + gi] = sz;
        G[(size_t)(gj + 3) * N_PTS + gi] = sw;
    }
}

// ---------------- dot0[n][k] = G[n][cpts[k]], c2[k] = x2[cpts[k]] ----------------
__global__ __launch_bounds__(256) void dot0_kernel(const float* __restrict__ G,
                                                   const int* __restrict__ cpts,
                                                   const float* __restrict__ x2,
                                                   float* __restrict__ dot,
                                                   float* __restrict__ c2) {
    int g = blockIdx.x * 256 + threadIdx.x;
    int n = g >> 6, k = g & 63;
    dot[g] = G[(size_t)n * N_PTS + cpts[k]];
    if (g < K_C) c2[g] = x2[cpts[g]];
}

// ---------------- fused iteration step: c2-update + assign + sort (+out) ----------------
// 1 block, 1024 threads. Reduction orders identical to the unfused kernels:
// c2 serial-ascending over prev order; assign wave-argmin tie->lowest k;
// counting sort with stable rank. Writes chbuf/order/cstart/tlast.
__global__ __launch_bounds__(1024) void step_kernel(const float* __restrict__ dotg,
                                                    float* __restrict__ c2,
                                                    int* __restrict__ chbuf,
                                                    int* __restrict__ order,
                                                    int* __restrict__ cstart,
                                                    int* __restrict__ tlast,
                                                    int it,
                                                    float* __restrict__ out_choice) {
    __shared__ int ch[N_PTS];
    __shared__ int cnt[K_C];
    __shared__ int cst[K_C + 1];
    __shared__ float c2s[K_C];
    const int t = threadIdx.x;

    // phase 0: c2[k] = mean over prev members (ascending order) of dot[m][k]
    if (it > 0 && t < K_C) {
        int b = cstart[t], e = cstart[t + 1];
        if (b != e) {
            float s = 0.f;
            for (int i = b; i < e; ++i) s += dotg[order[i] * K_C + t];
            c2[t] = s / (float)(e - b);
        }
    }
    __syncthreads();
    if (t < K_C) c2s[t] = c2[t];
    __syncthreads();

    // phase 1: assign (wave per point, 64 pts per wave)
    {
        const int wv = t >> 6, lane = t & 63;
        const float myc2 = c2s[lane];
        for (int n = wv * 64; n < wv * 64 + 64; ++n) {
            float v = fmaf(-2.f, dotg[n * K_C + lane], myc2);
            int bi = lane;
            #pragma unroll
            for (int m = 32; m; m >>= 1) {
                float v2 = __shfl_xor(v, m);
                int   i2 = __shfl_xor(bi, m);
                if (v2 < v || (v2 == v && i2 < bi)) { v = v2; bi = i2; }
            }
            if (lane == 0) ch[n] = bi;
        }
    }
    __syncthreads();

    // phase 2: counting sort + tlast
    if (t < K_C) cnt[t] = 0;
    __syncthreads();
    const int c = ch[t];
    atomicAdd(&cnt[c], 1);
    __syncthreads();
    if (t == 0) {
        int a = 0;
        for (int k = 0; k < K_C; ++k) { cst[k] = a; a += cnt[k]; }
        cst[K_C] = a;
    }
    __syncthreads();
    if (t <= K_C) cstart[t] = cst[t];
    if (t < K_C && cnt[t] > 0) tlast[t] = it;
    int r = 0;
    for (int m = 0; m < t; ++m) r += (ch[m] == c);
    order[cst[c] + r] = t;
    chbuf[it * N_PTS + t] = c;
    if (it == ITERS - 1) out_choice[t] = (float)c;
}

// ---------------- dot[n][k] = mean over members(k) of G[n][m] ----------------
__global__ __launch_bounds__(256) void dotup_kernel(const float* __restrict__ G,
                                                    const int* __restrict__ order,
                                                    const int* __restrict__ cstart,
                                                    float* __restrict__ dot) {
    __shared__ int ord[N_PTS];
    __shared__ int cst[K_C + 1];
    int t = threadIdx.x;
    #pragma unroll
    for (int i = 0; i < 4; ++i) ord[t + 256 * i] = order[t + 256 * i];
    if (t <= K_C) cst[t] = cstart[t];
    __syncthreads();
    int wid = t >> 6, lane = t & 63;
    int n = blockIdx.x * 4 + wid;
    int b = cst[lane], e = cst[lane + 1];
    if (b == e) return;                              // empty: keep old column
    const float* gr = G + (size_t)n * N_PTS;
    float s = 0.f;
    for (int i = b; i < e; ++i) s += gr[ord[i]];     // ascending order: deterministic
    dot[n * K_C + lane] = s / (float)(e - b);
}

// ---------------- init tlast ----------------
__global__ __launch_bounds__(64) void init_tlast_kernel(int* __restrict__ tlast) {
    tlast[threadIdx.x] = -1;
}

// ---------------- final centroids: exact fp32 means at last-nonempty iter ----------------
__global__ __launch_bounds__(256) void final_state_kernel(const float* __restrict__ X,
                                                          const int* __restrict__ chbuf,
                                                          const int* __restrict__ tlast,
                                                          float* __restrict__ state) {
    const int k = blockIdx.x;
    const int tk = tlast[k];
    if (tk < 0) return;                              // never nonempty: keep snapped
    __shared__ int chs[N_PTS];
    const int* src = chbuf + tk * N_PTS;
    const int t = threadIdx.x;
    #pragma unroll
    for (int i = 0; i < 4; ++i) chs[t + 256 * i] = src[t + 256 * i];
    __syncthreads();
    const size_t d = (size_t)blockIdx.y * 1024 + t * 4;
    float sx = 0.f, sy = 0.f, sz = 0.f, sw = 0.f;
    int cm = 0;
    for (int n = 0; n < N_PTS; ++n) {
        if (chs[n] == k) {                           // ascending n: deterministic
            ++cm;
            const float4 v = *reinterpret_cast<const float4*>(X + (size_t)n * D_DIM + d);
            sx += v.x; sy += v.y; sz += v.z; sw += v.w;
        }
    }
    float inv = 1.f / (float)cm;
    float4 o = {sx * inv, sy * inv, sz * inv, sw * inv};
    *reinterpret_cast<float4*>(state + (size_t)k * D_DIM + d) = o;
}

extern "C" void kernel_launch(void* const* d_in, const int* in_sizes, int n_in,
                              void* d_out, int out_size, void* d_ws, size_t ws_size,
                              hipStream_t stream) {
    const float* X  = (const float*)d_in[0];
    const float* C0 = (const float*)d_in[1];
    float* state      = (float*)d_out;
    float* out_choice = state + (size_t)K_C * D_DIM;

    char* w = (char*)d_ws;
    size_t off = 0;
    auto alloc = [&](size_t bytes) { void* p = w + off; off = (off + bytes + 255) & ~(size_t)255; return p; };
    unsigned short* Xh = (unsigned short*)alloc((size_t)N_PTS * D_DIM * 2);   // 201 MB
    unsigned short* Xl = (unsigned short*)alloc((size_t)N_PTS * D_DIM * 2);   // 201 MB
    unsigned short* Sh = (unsigned short*)alloc((size_t)K_C * D_DIM * 2);     // 12.6 MB
    unsigned short* Sl = (unsigned short*)alloc((size_t)K_C * D_DIM * 2);
    float* partial = (float*)alloc((size_t)SPLITD * N_PTS * K_C * 4);         // 16 MB
    float* Gpart   = (float*)alloc((size_t)NGRP * NPAIR * GT * GT * 4);       // 37.7 MB
    float* G       = (float*)alloc((size_t)N_PTS * N_PTS * 4);                // 4 MB
    float* dotb    = (float*)alloc((size_t)N_PTS * K_C * 4);
    float* x2p     = (float*)alloc((size_t)N_PTS * CCHK * 4);
    float* x2      = (float*)alloc((size_t)N_PTS * 4);
    float* c0sq    = (float*)alloc((size_t)K_C * CCHK * 4);
    float* dotg    = (float*)alloc((size_t)N_PTS * K_C * 4);
    float* c2      = (float*)alloc(256);
    int* cpts      = (int*)alloc(256);
    int* chbuf     = (int*)alloc((size_t)ITERS * N_PTS * 4);                  // 40 KB
    int* order     = (int*)alloc((size_t)N_PTS * 4);
    int* cstart    = (int*)alloc(512);
    int* tlast     = (int*)alloc(256);

    dim3 b256(256);

    // one-time: X -> bf16 hi/lo planes + x2
    convert_kernel<<<dim3(N_PTS, CCHK), b256, 0, stream>>>(X, Xh, Xl, x2p);
    reduce_sq_kernel<<<dim3(4), b256, 0, stream>>>(x2p, x2, N_PTS);

    // G = X.X^T (async-staged, XCD-cohort, ~1 epoch resident)
    gbuild_kernel<<<dim3(8 * NPAIR * (NGRP / 8)), b256, 0, stream>>>(Xh, Xl, Gpart);
    reduce_g_kernel<<<dim3(NPAIR, 16), b256, 0, stream>>>(Gpart, G);

    // init ('resuming'): snap each centroid to nearest sample
    convert_kernel<<<dim3(K_C, CCHK), b256, 0, stream>>>(C0, Sh, Sl, c0sq);
    mfma_dot_kernel<<<dim3(SPLITD, N_PTS / BM), b256, 0, stream>>>(Xh, Xl, Sh, Sl, partial);
    reduce_dot_kernel<<<dim3(N_PTS * K_C / 256), b256, 0, stream>>>(partial, dotb);
    argmin_n_kernel<<<K_C, b256, 0, stream>>>(dotb, x2, cpts);
    gather_kernel<<<dim3(K_C, NCHK), b256, 0, stream>>>(X, cpts, state);
    init_tlast_kernel<<<1, dim3(64), 0, stream>>>(tlast);
    dot0_kernel<<<dim3(N_PTS * K_C / 256), b256, 0, stream>>>(G, cpts, x2, dotg, c2);

    // 10 Lloyd iterations entirely on G (2 launches/iter; last iter 1)
    for (int it = 0; it < ITERS; ++it) {
        step_kernel<<<1, dim3(1024), 0, stream>>>(dotg, c2, chbuf, order, cstart,
                                                  tlast, it, out_choice);
        if (it < ITERS - 1)
            dotup_kernel<<<dim3(N_PTS / 4), b256, 0, stream>>>(G, order, cstart, dotg);
    }

    // final: exact fp32 means using each cluster's last-nonempty choice vector
    final_state_kernel<<<dim3(K_C, NCHK), b256, 0, stream>>>(X, chbuf, tlast, state);
}

// Round 11
// 1897.585 us; speedup vs baseline: 1.2840x; 1.2840x over previous
//
#include <hip/hip_runtime.h>
#include <cstddef>
#include <cstdint>

// K-means (Lloyd, 10 fixed iters): N=1024 pts, K=64 centroids, D=98304.
// d_in[0]=x f32[1024*98304], d_in[1]=centroid f32[64*98304]
// d_out = concat(final state [64*98304] f32, last choice [1024] as f32)
//
// Round 11: gbuild gets the m201 pipeline: double-buffered global_load_lds
// staging with COUNTED s_waitcnt vmcnt(8) + raw s_barrier (loads for chunk
// i+1 in flight across the barrier while chunk i computes; vmcnt never 0 in
// steady state). 64KB LDS (2x dbuf of A,B 16KB tiles), 2 blocks/CU. NGRP=16
// (round 10's lower-FETCH config). Swizzle identical to round 9 (absmax 0.0,
// 0 bank conflicts). Iteration loop reverted to round 9's unfused kernels
// (round 10's fusion coincided with an unexplained regression).

#define N_PTS  1024
#define K_C    64
#define D_DIM  98304
#define ITERS  10
#define SPLITD 64          // init dot kernel split
#define BM     64
#define DC     64
#define LDSP   72
#define NCHK   96          // D/1024
#define CCHK   12          // D/8192
#define NGRP   16          // seg-half groups (2 XCD-cohort epochs x 8)
#define SHPG   12          // seg-halves per group
#define SHW    512         // shorts per seg-half
#define NCHT   192         // chunks per block = SHPG * SHW/GDC
#define NPAIR  36          // 8x8 upper-triangle 128-tiles
#define GT     128
#define GDC    32          // dims per K-chunk

typedef __attribute__((ext_vector_type(8))) short bf16x8;
typedef __attribute__((ext_vector_type(8))) unsigned short ushort8;
typedef __attribute__((ext_vector_type(4))) float f32x4;

__device__ __forceinline__ unsigned short f2bf(float x) {   // RNE f32->bf16
    unsigned u = __float_as_uint(x);
    u = (u + 0x7FFFu + ((u >> 16) & 1u)) >> 16;
    return (unsigned short)u;
}
__device__ __forceinline__ float bf2f(unsigned short b) {
    return __uint_as_float((unsigned)b << 16);
}
__device__ __forceinline__ void cvt2(float x, unsigned short& h, unsigned short& l) {
    h = f2bf(x);
    l = f2bf(x - bf2f(h));
}

__device__ __forceinline__ void gload_lds16(const unsigned short* g, char* l) {
    __builtin_amdgcn_global_load_lds(
        (const __attribute__((address_space(1))) unsigned int*)g,
        (__attribute__((address_space(3))) unsigned int*)l, 16, 0, 0);
}

__device__ __forceinline__ float block_sum256(float s) {
    #pragma unroll
    for (int o = 32; o; o >>= 1) s += __shfl_down(s, o);
    __shared__ float red[4];
    int lane = threadIdx.x & 63, w = threadIdx.x >> 6;
    if (lane == 0) red[w] = s;
    __syncthreads();
    return red[0] + red[1] + red[2] + red[3];
}

// ---------------- convert rows fp32 -> bf16 hi/lo planes + sumsq partials ----------------
__global__ __launch_bounds__(256) void convert_kernel(const float* __restrict__ A,
                                                      unsigned short* __restrict__ Ph,
                                                      unsigned short* __restrict__ Pl,
                                                      float* __restrict__ sq_part) {
    const int n = blockIdx.x, j = blockIdx.y;
    const size_t base = (size_t)n * D_DIM + (size_t)j * 8192;
    const int t = threadIdx.x;
    float ss = 0.f;
    #pragma unroll
    for (int i = 0; i < 4; ++i) {
        size_t e = base + (size_t)i * 2048 + t * 8;
        float4 a = *reinterpret_cast<const float4*>(A + e);
        float4 b = *reinterpret_cast<const float4*>(A + e + 4);
        ss += a.x*a.x + a.y*a.y + a.z*a.z + a.w*a.w;
        ss += b.x*b.x + b.y*b.y + b.z*b.z + b.w*b.w;
        ushort4 h0, l0, h1, l1;
        cvt2(a.x, h0.x, l0.x); cvt2(a.y, h0.y, l0.y);
        cvt2(a.z, h0.z, l0.z); cvt2(a.w, h0.w, l0.w);
        cvt2(b.x, h1.x, l1.x); cvt2(b.y, h1.y, l1.y);
        cvt2(b.z, h1.z, l1.z); cvt2(b.w, h1.w, l1.w);
        *reinterpret_cast<ushort4*>(Ph + e)     = h0;
        *reinterpret_cast<ushort4*>(Ph + e + 4) = h1;
        *reinterpret_cast<ushort4*>(Pl + e)     = l0;
        *reinterpret_cast<ushort4*>(Pl + e + 4) = l1;
    }
    ss = block_sum256(ss);
    if (t == 0) sq_part[n * CCHK + j] = ss;
}

__global__ __launch_bounds__(256) void reduce_sq_kernel(const float* __restrict__ sq_part,
                                                        float* __restrict__ out, int rows) {
    int n = blockIdx.x * 256 + threadIdx.x;
    if (n >= rows) return;
    float s = 0.f;
    #pragma unroll
    for (int j = 0; j < CCHK; ++j) s += sq_part[n * CCHK + j];
    out[n] = s;
}

// ---------------- init dot vs C0: bf16 hi/lo x3 MFMA, A direct-global ----------------
__global__ __launch_bounds__(256) void mfma_dot_kernel(const unsigned short* __restrict__ Xh,
                                                       const unsigned short* __restrict__ Xl,
                                                       const unsigned short* __restrict__ Sh,
                                                       const unsigned short* __restrict__ Sl,
                                                       float* __restrict__ partial) {
    __shared__ alignas(16) short Bh[K_C][LDSP];
    __shared__ alignas(16) short Bl[K_C][LDSP];

    const int seg = blockIdx.x, nblk = blockIdx.y;
    const int t = threadIdx.x;
    const int wid = t >> 6, lane = t & 63;
    const int d_begin = seg * (D_DIM / SPLITD);
    const int NCH = (D_DIM / SPLITD) / DC;          // 24 (even)

    const int arow = nblk * BM + wid * 16 + (lane & 15);
    const int ko = (lane >> 4) * 8;
    const unsigned short* xh = Xh + (size_t)arow * D_DIM;
    const unsigned short* xl = Xl + (size_t)arow * D_DIM;

    const int sr = t >> 2, sc = (t & 3) * 16;
    const unsigned short* shp = Sh + (size_t)sr * D_DIM;
    const unsigned short* slp = Sl + (size_t)sr * D_DIM;

    ushort8 s0, s1, s2, s3;
    bf16x8 aEh0, aEh1, aEl0, aEl1;
    bf16x8 aOh0, aOh1, aOl0, aOl1;

    auto loadB = [&](int d0) {
        s0 = *reinterpret_cast<const ushort8*>(shp + d0 + sc);
        s1 = *reinterpret_cast<const ushort8*>(shp + d0 + sc + 8);
        s2 = *reinterpret_cast<const ushort8*>(slp + d0 + sc);
        s3 = *reinterpret_cast<const ushort8*>(slp + d0 + sc + 8);
    };
    auto storeB = [&]() {
        *reinterpret_cast<ushort8*>(&Bh[sr][sc])     = s0;
        *reinterpret_cast<ushort8*>(&Bh[sr][sc + 8]) = s1;
        *reinterpret_cast<ushort8*>(&Bl[sr][sc])     = s2;
        *reinterpret_cast<ushort8*>(&Bl[sr][sc + 8]) = s3;
    };

    f32x4 acc[4];
    #pragma unroll
    for (int i = 0; i < 4; ++i) acc[i] = f32x4{0.f, 0.f, 0.f, 0.f};

    #define LOADA(bh0, bh1, bl0, bl1, d0)                                        \
        bh0 = *reinterpret_cast<const bf16x8*>(xh + (d0) + ko);                  \
        bh1 = *reinterpret_cast<const bf16x8*>(xh + (d0) + 32 + ko);             \
        bl0 = *reinterpret_cast<const bf16x8*>(xl + (d0) + ko);                  \
        bl1 = *reinterpret_cast<const bf16x8*>(xl + (d0) + 32 + ko);

    #define MFMAS(ah0, ah1, al0, al1)                                            \
        _Pragma("unroll")                                                        \
        for (int nb = 0; nb < 4; ++nb) {                                         \
            const int br = nb * 16 + (lane & 15);                                \
            bf16x8 bh = *reinterpret_cast<const bf16x8*>(&Bh[br][ko]);           \
            bf16x8 bl = *reinterpret_cast<const bf16x8*>(&Bl[br][ko]);           \
            acc[nb] = __builtin_amdgcn_mfma_f32_16x16x32_bf16(ah0, bh, acc[nb], 0, 0, 0); \
            acc[nb] = __builtin_amdgcn_mfma_f32_16x16x32_bf16(ah0, bl, acc[nb], 0, 0, 0); \
            acc[nb] = __builtin_amdgcn_mfma_f32_16x16x32_bf16(al0, bh, acc[nb], 0, 0, 0); \
        }                                                                        \
        _Pragma("unroll")                                                        \
        for (int nb = 0; nb < 4; ++nb) {                                         \
            const int br = nb * 16 + (lane & 15);                                \
            bf16x8 bh = *reinterpret_cast<const bf16x8*>(&Bh[br][32 + ko]);      \
            bf16x8 bl = *reinterpret_cast<const bf16x8*>(&Bl[br][32 + ko]);      \
            acc[nb] = __builtin_amdgcn_mfma_f32_16x16x32_bf16(ah1, bh, acc[nb], 0, 0, 0); \
            acc[nb] = __builtin_amdgcn_mfma_f32_16x16x32_bf16(ah1, bl, acc[nb], 0, 0, 0); \
            acc[nb] = __builtin_amdgcn_mfma_f32_16x16x32_bf16(al1, bh, acc[nb], 0, 0, 0); \
        }

    loadB(d_begin);
    LOADA(aEh0, aEh1, aEl0, aEl1, d_begin);
    for (int c = 0; c < NCH; c += 2) {
        __syncthreads();
        storeB();
        __syncthreads();
        {
            int dn = d_begin + (c + 1) * DC;
            loadB(dn);
            LOADA(aOh0, aOh1, aOl0, aOl1, dn);
        }
        MFMAS(aEh0, aEh1, aEl0, aEl1);
        __syncthreads();
        storeB();
        __syncthreads();
        if (c + 2 < NCH) {
            int dn = d_begin + (c + 2) * DC;
            loadB(dn);
            LOADA(aEh0, aEh1, aEl0, aEl1, dn);
        }
        MFMAS(aOh0, aOh1, aOl0, aOl1);
    }
    #undef LOADA
    #undef MFMAS

    #pragma unroll
    for (int nb = 0; nb < 4; ++nb)
        #pragma unroll
        for (int r = 0; r < 4; ++r) {
            int row = wid * 16 + (lane >> 4) * 4 + r;
            int col = nb * 16 + (lane & 15);
            int n = nblk * BM + row;
            partial[((size_t)seg * N_PTS + n) * K_C + col] = acc[nb][r];
        }
}

__global__ __launch_bounds__(256) void reduce_dot_kernel(const float* __restrict__ partial,
                                                         float* __restrict__ dot) {
    int i = blockIdx.x * 256 + threadIdx.x;
    float s = 0.f;
    #pragma unroll 8
    for (int p = 0; p < SPLITD; ++p) s += partial[(size_t)p * N_PTS * K_C + i];
    dot[i] = s;
}

__global__ __launch_bounds__(256) void argmin_n_kernel(const float* __restrict__ dot,
                                                       const float* __restrict__ x2,
                                                       int* __restrict__ choice_pts) {
    int k = blockIdx.x;
    float best = 3.4e38f; int bi = N_PTS;
    for (int n = threadIdx.x; n < N_PTS; n += 256) {
        float v = fmaf(-2.f, dot[n * K_C + k], x2[n]);
        if (v < best || (v == best && n < bi)) { best = v; bi = n; }
    }
    #pragma unroll
    for (int off = 32; off; off >>= 1) {
        float v2 = __shfl_down(best, off);
        int   i2 = __shfl_down(bi, off);
        if (v2 < best || (v2 == best && i2 < bi)) { best = v2; bi = i2; }
    }
    __shared__ float bv[4]; __shared__ int bix[4];
    int lane = threadIdx.x & 63, wid = threadIdx.x >> 6;
    if (lane == 0) { bv[wid] = best; bix[wid] = bi; }
    __syncthreads();
    if (threadIdx.x == 0) {
        for (int w = 1; w < 4; ++w)
            if (bv[w] < best || (bv[w] == best && bix[w] < bi)) { best = bv[w]; bi = bix[w]; }
        choice_pts[k] = bi;
    }
}

// ---------------- gather snapped centroids (exact fp32) ----------------
__global__ __launch_bounds__(256) void gather_kernel(const float* __restrict__ X,
                                                     const int* __restrict__ choice_pts,
                                                     float* __restrict__ state) {
    int k = blockIdx.x;
    int c = choice_pts[k];
    size_t d = (size_t)blockIdx.y * 1024 + threadIdx.x * 4;
    float4 v = *reinterpret_cast<const float4*>(X + (size_t)c * D_DIM + d);
    *reinterpret_cast<float4*>(state + (size_t)k * D_DIM + d) = v;
}

// ---------------- G = X.X^T: dbuf async staging + counted vmcnt + cohort ----------------
// 576 blocks; id=(g%8)+8*(p+36*(g/8)) keeps all 36 pairs of a group on one
// XCD. 64KB LDS: 2 x {A,B} 16KB tiles. Steady state: chunk i+1's 32
// global_load_lds stay in flight across the barrier (vmcnt(8) per wave =
// own 8 of chunk i landed); compute chunk i meanwhile. Raw s_barrier (no
// __syncthreads vmcnt(0) drain) + sched_barrier fences. Swizzle = round 9:
// logical word w of row r at slot (w^(r&7)); source pre-swizzled per lane.
__global__ __launch_bounds__(256, 2) void gbuild_kernel(const unsigned short* __restrict__ Xh,
                                                        const unsigned short* __restrict__ Xl,
                                                        float* __restrict__ Gpart) {
    __shared__ alignas(16) char L[65536];           // [buf0: A|B][buf1: A|B]

    const int id = blockIdx.x;
    const int xr = id & 7, q = id >> 3;
    const int p = q % NPAIR;
    const int g = ((q / NPAIR) << 3) + xr;          // 0..15
    int bi = 0, rem = p, rl = 8;
    while (rem >= rl) { rem -= rl; --rl; ++bi; }
    const int bj = bi + rem;

    const int t = threadIdx.x;
    const int wid = t >> 6, lane = t & 63;
    const int wr = wid >> 1, wc = wid & 1;

    // staging: waves 0-1 -> A tile, waves 2-3 -> B tile; 8 instrs/wave/chunk
    const int isA = (wid < 2) ? 1 : 0;
    const int i0 = (wid & 1) * 8;                   // instr indices i0..i0+7
    const int tileoff = isA ? 0 : 16384;
    const int rowbase = (isA ? bi : bj) * GT;
    const int lw = (lane & 7) ^ (lane >> 3);        // logical word this lane fetches
    const unsigned short* plane = (lw & 4) ? Xl : Xh;
    const unsigned short* gbase[8];
    #pragma unroll
    for (int j = 0; j < 8; ++j)
        gbase[j] = plane + (size_t)(rowbase + (i0 + j) * 8 + (lane >> 3)) * D_DIM + (lw & 3) * 8;

    // read side: slot = w ^ (row&7); row&7 == lane&7 for all fragments
    const int sh = (lane >> 4) ^ (lane & 7);        // hi-plane slot (w = lane>>4)
    const int sl = (4 + (lane >> 4)) ^ (lane & 7);  // lo-plane slot (w = 4+lane>>4)
    const int ra0 = (wr * 64 + (lane & 15)) * 128;          // A row byte base
    const int rb0 = 16384 + (wc * 64 + (lane & 15)) * 128;  // B row byte base

    f32x4 acc[4][4];
    #pragma unroll
    for (int i = 0; i < 4; ++i)
        #pragma unroll
        for (int j = 0; j < 4; ++j) acc[i][j] = f32x4{0.f, 0.f, 0.f, 0.f};

    auto issue = [&](int idx) {
        const int d0 = (g + ((idx >> 4) << 4)) * SHW + (idx & 15) * GDC;
        char* dst = L + ((idx & 1) << 15) + tileoff + i0 * 1024;
        #pragma unroll
        for (int j = 0; j < 8; ++j)
            gload_lds16(gbase[j] + d0, dst + j * 1024);
    };

    issue(0);
    for (int idx = 0; idx < NCHT; ++idx) {
        if (idx + 1 < NCHT) {
            issue(idx + 1);                                    // prefetch next chunk
            asm volatile("s_waitcnt vmcnt(8)" ::: "memory");   // own chunk-idx loads landed
        } else {
            asm volatile("s_waitcnt vmcnt(0)" ::: "memory");
        }
        __builtin_amdgcn_s_barrier();                          // all waves' chunk-idx landed
        __builtin_amdgcn_sched_barrier(0);
        const char* base = L + ((idx & 1) << 15);
        bf16x8 ah[4], al[4];
        #pragma unroll
        for (int fi = 0; fi < 4; ++fi) {
            ah[fi] = *reinterpret_cast<const bf16x8*>(base + ra0 + fi * 2048 + sh * 16);
            al[fi] = *reinterpret_cast<const bf16x8*>(base + ra0 + fi * 2048 + sl * 16);
        }
        #pragma unroll
        for (int fj = 0; fj < 4; ++fj) {
            bf16x8 bh = *reinterpret_cast<const bf16x8*>(base + rb0 + fj * 2048 + sh * 16);
            bf16x8 bl = *reinterpret_cast<const bf16x8*>(base + rb0 + fj * 2048 + sl * 16);
            #pragma unroll
            for (int fi = 0; fi < 4; ++fi) {
                acc[fi][fj] = __builtin_amdgcn_mfma_f32_16x16x32_bf16(ah[fi], bh, acc[fi][fj], 0, 0, 0);
                acc[fi][fj] = __builtin_amdgcn_mfma_f32_16x16x32_bf16(ah[fi], bl, acc[fi][fj], 0, 0, 0);
                acc[fi][fj] = __builtin_amdgcn_mfma_f32_16x16x32_bf16(al[fi], bh, acc[fi][fj], 0, 0, 0);
            }
        }
        __builtin_amdgcn_sched_barrier(0);
        __builtin_amdgcn_s_barrier();              // all reads of this buffer done
    }

    float* gp = Gpart + ((size_t)g * NPAIR + p) * (GT * GT);
    #pragma unroll
    for (int fi = 0; fi < 4; ++fi)
        #pragma unroll
        for (int fj = 0; fj < 4; ++fj)
            #pragma unroll
            for (int r2 = 0; r2 < 4; ++r2) {
                int row = wr * 64 + fi * 16 + (lane >> 4) * 4 + r2;
                int col = wc * 64 + fj * 16 + (lane & 15);
                gp[row * GT + col] = acc[fi][fj][r2];
            }
}

// ---------------- reduce G partials over groups + mirror to lower triangle ----------------
__global__ __launch_bounds__(256) void reduce_g_kernel(const float* __restrict__ Gpart,
                                                       float* __restrict__ G) {
    const int p = blockIdx.x, blk = blockIdx.y;     // grid (NPAIR, 16)
    int bi = 0, rem = p, rl = 8;
    while (rem >= rl) { rem -= rl; --rl; ++bi; }
    const int bj = bi + rem;
    const int e0 = blk * 1024 + threadIdx.x * 4;
    float sx = 0.f, sy = 0.f, sz = 0.f, sw = 0.f;
    #pragma unroll 8
    for (int g = 0; g < NGRP; ++g) {
        const float4 v = *reinterpret_cast<const float4*>(
            Gpart + ((size_t)g * NPAIR + p) * (GT * GT) + e0);
        sx += v.x; sy += v.y; sz += v.z; sw += v.w;
    }
    const int row = e0 >> 7, col = e0 & 127;
    const int gi = bi * GT + row, gj = bj * GT + col;
    float4 o = {sx, sy, sz, sw};
    *reinterpret_cast<float4*>(&G[(size_t)gi * N_PTS + gj]) = o;
    if (bi != bj) {                                 // mirror (single writer per elem)
        G[(size_t)(gj + 0) * N_PTS + gi] = sx;
        G[(size_t)(gj + 1) * N_PTS + gi] = sy;
        G[(size_t)(gj + 2) * N_PTS + gi] = sz;
        G[(size_t)(gj + 3) * N_PTS + gi] = sw;
    }
}

// ---------------- dot0[n][k] = G[n][cpts[k]], c2[k] = x2[cpts[k]] ----------------
__global__ __launch_bounds__(256) void dot0_kernel(const float* __restrict__ G,
                                                   const int* __restrict__ cpts,
                                                   const float* __restrict__ x2,
                                                   float* __restrict__ dot,
                                                   float* __restrict__ c2) {
    int g = blockIdx.x * 256 + threadIdx.x;
    int n = g >> 6, k = g & 63;
    dot[g] = G[(size_t)n * N_PTS + cpts[k]];
    if (g < K_C) c2[g] = x2[cpts[g]];
}

// ---------------- assign: argmin over K=64 (wave per point) ----------------
__global__ __launch_bounds__(256) void assign_g_kernel(const float* __restrict__ dot,
                                                       const float* __restrict__ c2,
                                                       int* __restrict__ choice_it) {
    int wid = threadIdx.x >> 6, lane = threadIdx.x & 63;
    int n = blockIdx.x * 4 + wid;
    float v = fmaf(-2.f, dot[n * K_C + lane], c2[lane]);
    int bi = lane;
    #pragma unroll
    for (int m = 32; m; m >>= 1) {
        float v2 = __shfl_xor(v, m);
        int   i2 = __shfl_xor(bi, m);
        if (v2 < v || (v2 == v && i2 < bi)) { v = v2; bi = i2; }
    }
    if (lane == 0) choice_it[n] = bi;
}

// ---------------- counting sort + tlast (1 block, 1024 thr, deterministic) ----------------
__global__ __launch_bounds__(1024) void sort2_kernel(const int* __restrict__ choice,
                                                     int* __restrict__ order,
                                                     int* __restrict__ cstart,
                                                     int* __restrict__ tlast,
                                                     int it) {
    __shared__ int ch[N_PTS];
    __shared__ int cnt[K_C];
    __shared__ int cst[K_C + 1];
    int t = threadIdx.x;
    if (t < K_C) cnt[t] = 0;
    __syncthreads();
    int c = choice[t];
    ch[t] = c;
    atomicAdd(&cnt[c], 1);
    __syncthreads();
    if (t == 0) {
        int a = 0;
        for (int k = 0; k < K_C; ++k) { cst[k] = a; a += cnt[k]; }
        cst[K_C] = a;
    }
    __syncthreads();
    if (t <= K_C) cstart[t] = cst[t];
    if (t < K_C && cnt[t] > 0) tlast[t] = it;
    int r = 0;
    for (int m = 0; m < t; ++m) r += (ch[m] == c);
    order[cst[c] + r] = t;
}

// ---------------- dot[n][k] = mean over members(k) of G[n][m] ----------------
__global__ __launch_bounds__(256) void dotup_kernel(const float* __restrict__ G,
                                                    const int* __restrict__ order,
                                                    const int* __restrict__ cstart,
                                                    float* __restrict__ dot) {
    __shared__ int ord[N_PTS];
    __shared__ int cst[K_C + 1];
    int t = threadIdx.x;
    #pragma unroll
    for (int i = 0; i < 4; ++i) ord[t + 256 * i] = order[t + 256 * i];
    if (t <= K_C) cst[t] = cstart[t];
    __syncthreads();
    int wid = t >> 6, lane = t & 63;
    int n = blockIdx.x * 4 + wid;
    int b = cst[lane], e = cst[lane + 1];
    if (b == e) return;                              // empty: keep old column
    const float* gr = G + (size_t)n * N_PTS;
    float s = 0.f;
    for (int i = b; i < e; ++i) s += gr[ord[i]];     // ascending order: deterministic
    dot[n * K_C + lane] = s / (float)(e - b);
}

// ---------------- c2[k] = mean over members(k) of dot[m][k] ----------------
__global__ __launch_bounds__(64) void c2up_kernel(const float* __restrict__ dot,
                                                  const int* __restrict__ order,
                                                  const int* __restrict__ cstart,
                                                  float* __restrict__ c2) {
    int k = threadIdx.x;
    int b = cstart[k], e = cstart[k + 1];
    if (b == e) return;                              // empty: keep old
    float s = 0.f;
    for (int i = b; i < e; ++i) s += dot[order[i] * K_C + k];
    c2[k] = s / (float)(e - b);
}

// ---------------- init tlast ----------------
__global__ __launch_bounds__(64) void init_tlast_kernel(int* __restrict__ tlast) {
    tlast[threadIdx.x] = -1;
}

// ---------------- final centroids: exact fp32 means at last-nonempty iter ----------------
__global__ __launch_bounds__(256) void final_state_kernel(const float* __restrict__ X,
                                                          const int* __restrict__ chbuf,
                                                          const int* __restrict__ tlast,
                                                          float* __restrict__ state) {
    const int k = blockIdx.x;
    const int tk = tlast[k];
    if (tk < 0) return;                              // never nonempty: keep snapped
    __shared__ int chs[N_PTS];
    const int* src = chbuf + tk * N_PTS;
    const int t = threadIdx.x;
    #pragma unroll
    for (int i = 0; i < 4; ++i) chs[t + 256 * i] = src[t + 256 * i];
    __syncthreads();
    const size_t d = (size_t)blockIdx.y * 1024 + t * 4;
    float sx = 0.f, sy = 0.f, sz = 0.f, sw = 0.f;
    int cm = 0;
    for (int n = 0; n < N_PTS; ++n) {
        if (chs[n] == k) {                           // ascending n: deterministic
            ++cm;
            const float4 v = *reinterpret_cast<const float4*>(X + (size_t)n * D_DIM + d);
            sx += v.x; sy += v.y; sz += v.z; sw += v.w;
        }
    }
    float inv = 1.f / (float)cm;
    float4 o = {sx * inv, sy * inv, sz * inv, sw * inv};
    *reinterpret_cast<float4*>(state + (size_t)k * D_DIM + d) = o;
}

__global__ __launch_bounds__(256) void choice_out_kernel(const int* __restrict__ choice,
                                                         float* __restrict__ out) {
    int n = blockIdx.x * 256 + threadIdx.x;
    if (n < N_PTS) out[n] = (float)choice[n];
}

extern "C" void kernel_launch(void* const* d_in, const int* in_sizes, int n_in,
                              void* d_out, int out_size, void* d_ws, size_t ws_size,
                              hipStream_t stream) {
    const float* X  = (const float*)d_in[0];
    const float* C0 = (const float*)d_in[1];
    float* state      = (float*)d_out;
    float* out_choice = state + (size_t)K_C * D_DIM;

    char* w = (char*)d_ws;
    size_t off = 0;
    auto alloc = [&](size_t bytes) { void* p = w + off; off = (off + bytes + 255) & ~(size_t)255; return p; };
    unsigned short* Xh = (unsigned short*)alloc((size_t)N_PTS * D_DIM * 2);   // 201 MB
    unsigned short* Xl = (unsigned short*)alloc((size_t)N_PTS * D_DIM * 2);   // 201 MB
    unsigned short* Sh = (unsigned short*)alloc((size_t)K_C * D_DIM * 2);     // 12.6 MB
    unsigned short* Sl = (unsigned short*)alloc((size_t)K_C * D_DIM * 2);
    float* partial = (float*)alloc((size_t)SPLITD * N_PTS * K_C * 4);         // 16 MB
    float* Gpart   = (float*)alloc((size_t)NGRP * NPAIR * GT * GT * 4);       // 37.7 MB
    float* G       = (float*)alloc((size_t)N_PTS * N_PTS * 4);                // 4 MB
    float* dotb    = (float*)alloc((size_t)N_PTS * K_C * 4);
    float* x2p     = (float*)alloc((size_t)N_PTS * CCHK * 4);
    float* x2      = (float*)alloc((size_t)N_PTS * 4);
    float* c0sq    = (float*)alloc((size_t)K_C * CCHK * 4);
    float* dotg    = (float*)alloc((size_t)N_PTS * K_C * 4);
    float* c2      = (float*)alloc(256);
    int* cpts      = (int*)alloc(256);
    int* chbuf     = (int*)alloc((size_t)ITERS * N_PTS * 4);                  // 40 KB
    int* order     = (int*)alloc((size_t)N_PTS * 4);
    int* cstart    = (int*)alloc(512);
    int* tlast     = (int*)alloc(256);

    dim3 b256(256);

    // one-time: X -> bf16 hi/lo planes + x2
    convert_kernel<<<dim3(N_PTS, CCHK), b256, 0, stream>>>(X, Xh, Xl, x2p);
    reduce_sq_kernel<<<dim3(4), b256, 0, stream>>>(x2p, x2, N_PTS);

    // G = X.X^T (dbuf async staging, XCD-cohort)
    gbuild_kernel<<<dim3(8 * NPAIR * (NGRP / 8)), b256, 0, stream>>>(Xh, Xl, Gpart);
    reduce_g_kernel<<<dim3(NPAIR, 16), b256, 0, stream>>>(Gpart, G);

    // init ('resuming'): snap each centroid to nearest sample
    convert_kernel<<<dim3(K_C, CCHK), b256, 0, stream>>>(C0, Sh, Sl, c0sq);
    mfma_dot_kernel<<<dim3(SPLITD, N_PTS / BM), b256, 0, stream>>>(Xh, Xl, Sh, Sl, partial);
    reduce_dot_kernel<<<dim3(N_PTS * K_C / 256), b256, 0, stream>>>(partial, dotb);
    argmin_n_kernel<<<K_C, b256, 0, stream>>>(dotb, x2, cpts);
    gather_kernel<<<dim3(K_C, NCHK), b256, 0, stream>>>(X, cpts, state);
    init_tlast_kernel<<<1, dim3(64), 0, stream>>>(tlast);
    dot0_kernel<<<dim3(N_PTS * K_C / 256), b256, 0, stream>>>(G, cpts, x2, dotg, c2);

    // 10 Lloyd iterations entirely on G
    for (int it = 0; it < ITERS; ++it) {
        assign_g_kernel<<<dim3(N_PTS / 4), b256, 0, stream>>>(dotg, c2, chbuf + it * N_PTS);
        sort2_kernel<<<1, dim3(1024), 0, stream>>>(chbuf + it * N_PTS, order, cstart, tlast, it);
        if (it < ITERS - 1) {
            dotup_kernel<<<dim3(N_PTS / 4), b256, 0, stream>>>(G, order, cstart, dotg);
            c2up_kernel<<<1, dim3(64), 0, stream>>>(dotg, order, cstart, c2);
        }
    }

    // final: exact fp32 means using each cluster's last-nonempty choice vector
    final_state_kernel<<<dim3(K_C, NCHK), b256, 0, stream>>>(X, chbuf, tlast, state);
    choice_out_kernel<<<dim3(N_PTS / 256), b256, 0, stream>>>(chbuf + (ITERS - 1) * N_PTS, out_choice);
}